// Round 1
// baseline (19609.657 us; speedup 1.0000x reference)
//
#include <hip/hip_runtime.h>
#include <hip/hip_bf16.h>
#include <cstdint>

#define HD 768
#define VOC 21128
#define VOCP 21248
#define NSTEPS 511
#define MROWS 4088      // 511*8
#define MPAD 4096
#define NBL 192         // lstm blocks (co-resident)

typedef float f32x4 __attribute__((ext_vector_type(4)));
typedef short short8 __attribute__((ext_vector_type(8)));

// ---- workspace layout (bytes) ----
// 0        : barrier [cnt, rel]
// 256      : hbuf[2][8][768] f32           (49152)
// 49664    : Hall[4096][768] f32           (12582912)
// 12632576 : WdT[768][768] f32             (2359296)
// 14991872 : T[4096][768] bf16             (6291456)
// 21283328 : WvB[21248][768] bf16          (32636928)  -> end 53920256
#define OFF_HBUF 256
#define OFF_HALL 49664
#define OFF_WDT  12632576ULL
#define OFF_T    14991872ULL
#define OFF_WV   21283328ULL

__device__ __forceinline__ unsigned short f2bf(float x) {
  unsigned u = __float_as_uint(x);
  u += 0x7FFFu + ((u >> 16) & 1u);   // RNE
  return (unsigned short)(u >> 16);
}

__device__ __forceinline__ void gl_lds16(const void* g, void* l) {
  __builtin_amdgcn_global_load_lds(
      (const __attribute__((address_space(1))) void*)g,
      (__attribute__((address_space(3))) void*)l, 16, 0, 0);
}

// ---------------- prep: WdT transpose, Wv->bf16 (padded), barrier init ----
__global__ __launch_bounds__(256) void prep_kernel(
    const float* __restrict__ Wd, float* __restrict__ WdT,
    const float* __restrict__ Wv, unsigned short* __restrict__ WvB,
    int* __restrict__ bar) {
  unsigned idx = blockIdx.x * 256 + threadIdx.x;
  if (idx == 0) { bar[0] = 0; bar[1] = 0; }
  unsigned stride = gridDim.x * 256;
  for (unsigned i = idx; i < HD * HD; i += stride) {
    unsigned k = i / HD, j = i - k * HD;
    WdT[i] = Wd[j * HD + k];           // WdT[k][j] = Wd[j][k]
  }
  const unsigned NV = (unsigned)VOCP * HD, NVr = (unsigned)VOC * HD;
  for (unsigned i = idx; i < NV; i += stride)
    WvB[i] = f2bf(i < NVr ? Wv[i] : 0.f);
}

// ---------------- lstm: persistent, 192 blocks, grid barrier per step ------
__global__ __launch_bounds__(256) void lstm_kernel(
    const float* __restrict__ cls, const float* __restrict__ Wih,
    const float* __restrict__ Whh, const float* __restrict__ bih,
    const float* __restrict__ bhh, float* __restrict__ hbuf,
    float* __restrict__ Hall, int* __restrict__ bar) {
  __shared__ float h_lds[8 * HD];      // current h (or cls), [b][k]
  __shared__ float red[4][16][8];      // per-wave partial sums
  __shared__ float gval[16][8];        // final gate values
  const int t = threadIdx.x;
  const int blk = blockIdx.x;
  const int p_ = t & 7;                // row-pair 0..7 (16 rows/block)
  const int s_ = t >> 3;               // k-slice 0..31 (24 k each)
  const int ks = s_ * 24;
  const int r0 = 2 * p_, r1 = r0 + 1;  // local rows; gate=r>>2, unit=r&3
  const int grow0 = (r0 >> 2) * HD + blk * 4 + (r0 & 3);
  const int grow1 = (r1 >> 2) * HD + blk * 4 + (r1 & 3);
  float w0[24], w1[24];
#pragma unroll
  for (int j = 0; j < 24; ++j) {
    w0[j] = Wih[(size_t)grow0 * HD + ks + j];
    w1[j] = Wih[(size_t)grow1 * HD + ks + j];
  }
  float bias = 0.f;
  if (t < 128) {
    int r = t >> 3;
    int gr = (r >> 2) * HD + blk * 4 + (r & 3);
    bias = bih[gr] + bhh[gr];
  }
  float cstate = 0.f;

  auto do_step = [&](float* __restrict__ hout, float* __restrict__ hall_row) {
    float acc0[8], acc1[8];
#pragma unroll
    for (int b = 0; b < 8; ++b) { acc0[b] = 0.f; acc1[b] = 0.f; }
#pragma unroll
    for (int b = 0; b < 8; ++b) {
      const float* hb = &h_lds[b * HD + ks];
#pragma unroll
      for (int j4 = 0; j4 < 6; ++j4) {
        f32x4 hv = *reinterpret_cast<const f32x4*>(hb + j4 * 4);
#pragma unroll
        for (int e = 0; e < 4; ++e) {
          acc0[b] = fmaf(w0[j4 * 4 + e], hv[e], acc0[b]);
          acc1[b] = fmaf(w1[j4 * 4 + e], hv[e], acc1[b]);
        }
      }
    }
#pragma unroll
    for (int b = 0; b < 8; ++b) {   // reduce over the wave's 8 k-slices
      acc0[b] += __shfl_xor(acc0[b], 8);
      acc0[b] += __shfl_xor(acc0[b], 16);
      acc0[b] += __shfl_xor(acc0[b], 32);
      acc1[b] += __shfl_xor(acc1[b], 8);
      acc1[b] += __shfl_xor(acc1[b], 16);
      acc1[b] += __shfl_xor(acc1[b], 32);
    }
    const int lane = t & 63, wv = t >> 6;
    if (lane < 8) {
#pragma unroll
      for (int b = 0; b < 8; ++b) {
        red[wv][2 * lane][b] = acc0[b];
        red[wv][2 * lane + 1][b] = acc1[b];
      }
    }
    __syncthreads();
    if (t < 128) {
      int r = t >> 3, b = t & 7;
      gval[r][b] = red[0][r][b] + red[1][r][b] + red[2][r][b] + red[3][r][b] + bias;
    }
    __syncthreads();
    if (t < 32) {
      int ul = t >> 3, b = t & 7;
      float gi = gval[ul][b], gf = gval[4 + ul][b];
      float gg = gval[8 + ul][b], go = gval[12 + ul][b];
      float iv = 1.f / (1.f + expf(-gi));
      float fv = 1.f / (1.f + expf(-gf));
      float gv = tanhf(gg);
      float ov = 1.f / (1.f + expf(-go));
      cstate = fv * cstate + iv * gv;
      float hn = ov * tanhf(cstate);
      int u = blk * 4 + ul;
      hout[b * HD + u] = hn;
      if (hall_row) hall_row[(size_t)b * HD + u] = hn;
    }
  };

  auto gbar = [&](int gen) {
    __threadfence();
    __syncthreads();
    if (t == 0) {
      int old = __hip_atomic_fetch_add(&bar[0], 1, __ATOMIC_ACQ_REL, __HIP_MEMORY_SCOPE_AGENT);
      if (old == NBL - 1) {
        __hip_atomic_store(&bar[0], 0, __ATOMIC_RELAXED, __HIP_MEMORY_SCOPE_AGENT);
        __hip_atomic_store(&bar[1], gen, __ATOMIC_RELEASE, __HIP_MEMORY_SCOPE_AGENT);
      } else {
        while (__hip_atomic_load(&bar[1], __ATOMIC_ACQUIRE, __HIP_MEMORY_SCOPE_AGENT) != gen)
          __builtin_amdgcn_s_sleep(2);
      }
    }
    __syncthreads();
    __threadfence();
  };

  // pre-step: h1 = cell(cls, 0, 0) -> gates = cls@Wih^T + (bih+bhh)
  for (int i = t; i < 8 * HD / 4; i += 256)
    reinterpret_cast<f32x4*>(h_lds)[i] = reinterpret_cast<const f32x4*>(cls)[i];
  __syncthreads();
  do_step(hbuf, nullptr);
  gbar(1);
  // switch to combined weights W_ih + W_hh
#pragma unroll
  for (int j = 0; j < 24; ++j) {
    w0[j] += Whh[(size_t)grow0 * HD + ks + j];
    w1[j] += Whh[(size_t)grow1 * HD + ks + j];
  }
  for (int it = 0; it < NSTEPS; ++it) {
    const float* hin = hbuf + (it & 1) * (8 * HD);
    float* hout = hbuf + ((it & 1) ^ 1) * (8 * HD);
    for (int i = t; i < 8 * HD / 4; i += 256)
      reinterpret_cast<f32x4*>(h_lds)[i] = reinterpret_cast<const f32x4*>(hin)[i];
    __syncthreads();
    do_step(hout, Hall + (size_t)it * 8 * HD);
    gbar(it + 2);
  }
}

// ---------------- head: dense + gelu(erf) + LayerNorm -> T (bf16) ----------
__global__ __launch_bounds__(256) void head_kernel(
    const float* __restrict__ Hall, const float* __restrict__ WdT,
    const float* __restrict__ bd, const float* __restrict__ gamma,
    const float* __restrict__ beta, unsigned short* __restrict__ Tm) {
  __shared__ float hT[HD][16];
  __shared__ float rbuf[4][16];
  __shared__ float mu_s[16], rs_s[16];
  const int t = threadIdx.x;
  const int r0 = blockIdx.x * 16;
  {
    const int row = t & 15, ksl = t >> 4;
    const float* src = Hall + (size_t)(r0 + row) * HD + ksl * 48;
#pragma unroll
    for (int i = 0; i < 12; ++i) {
      f32x4 v = *reinterpret_cast<const f32x4*>(src + i * 4);
      int k = ksl * 48 + i * 4;
      hT[k][row] = v[0]; hT[k + 1][row] = v[1];
      hT[k + 2][row] = v[2]; hT[k + 3][row] = v[3];
    }
  }
  __syncthreads();
  float a0[16], a1[16], a2[16];
#pragma unroll
  for (int r = 0; r < 16; ++r) { a0[r] = 0.f; a1[r] = 0.f; a2[r] = 0.f; }
  for (int k = 0; k < HD; ++k) {
    float wa = WdT[(size_t)k * HD + t];
    float wb = WdT[(size_t)k * HD + t + 256];
    float wc = WdT[(size_t)k * HD + t + 512];
    f32x4 hv4[4];
#pragma unroll
    for (int q = 0; q < 4; ++q)
      hv4[q] = *reinterpret_cast<const f32x4*>(&hT[k][q * 4]);
#pragma unroll
    for (int r = 0; r < 16; ++r) {
      float hv = hv4[r >> 2][r & 3];
      a0[r] = fmaf(wa, hv, a0[r]);
      a1[r] = fmaf(wb, hv, a1[r]);
      a2[r] = fmaf(wc, hv, a2[r]);
    }
  }
  float g0 = gamma[t], g1 = gamma[t + 256], g2 = gamma[t + 512];
  float be0 = beta[t], be1 = beta[t + 256], be2 = beta[t + 512];
  float bd0 = bd[t], bd1 = bd[t + 256], bd2 = bd[t + 512];
#pragma unroll
  for (int r = 0; r < 16; ++r) {
    float x;
    x = a0[r] + bd0; a0[r] = 0.5f * x * (1.f + erff(x * 0.7071067811865476f));
    x = a1[r] + bd1; a1[r] = 0.5f * x * (1.f + erff(x * 0.7071067811865476f));
    x = a2[r] + bd2; a2[r] = 0.5f * x * (1.f + erff(x * 0.7071067811865476f));
  }
  float ps[16];
  const int lane = t & 63, wv = t >> 6;
#pragma unroll
  for (int r = 0; r < 16; ++r) ps[r] = a0[r] + a1[r] + a2[r];
#pragma unroll
  for (int r = 0; r < 16; ++r)
#pragma unroll
    for (int m = 1; m < 64; m <<= 1) ps[r] += __shfl_xor(ps[r], m);
  if (lane == 0) {
#pragma unroll
    for (int r = 0; r < 16; ++r) rbuf[wv][r] = ps[r];
  }
  __syncthreads();
  if (t < 16) mu_s[t] = (rbuf[0][t] + rbuf[1][t] + rbuf[2][t] + rbuf[3][t]) * (1.f / HD);
  __syncthreads();
#pragma unroll
  for (int r = 0; r < 16; ++r) {
    float mu = mu_s[r];
    float d0 = a0[r] - mu, d1 = a1[r] - mu, d2 = a2[r] - mu;
    ps[r] = d0 * d0 + d1 * d1 + d2 * d2;
  }
#pragma unroll
  for (int r = 0; r < 16; ++r)
#pragma unroll
    for (int m = 1; m < 64; m <<= 1) ps[r] += __shfl_xor(ps[r], m);
  if (lane == 0) {
#pragma unroll
    for (int r = 0; r < 16; ++r) rbuf[wv][r] = ps[r];
  }
  __syncthreads();
  if (t < 16)
    rs_s[t] = 1.f / sqrtf((rbuf[0][t] + rbuf[1][t] + rbuf[2][t] + rbuf[3][t]) * (1.f / HD) + 1e-12f);
  __syncthreads();
#pragma unroll
  for (int r = 0; r < 16; ++r) {
    float mu = mu_s[r], rs = rs_s[r];
    size_t ro = (size_t)(r0 + r) * HD;
    Tm[ro + t]       = f2bf((a0[r] - mu) * rs * g0 + be0);
    Tm[ro + t + 256] = f2bf((a1[r] - mu) * rs * g1 + be1);
    Tm[ro + t + 512] = f2bf((a2[r] - mu) * rs * g2 + be2);
  }
}

// ---------------- decoder GEMM: out = T @ WvB^T + bvoc  (bf16 MFMA) -------
__global__ __launch_bounds__(256) void gemm_kernel(
    const unsigned short* __restrict__ Tm, const unsigned short* __restrict__ Wv,
    const float* __restrict__ bvoc, float* __restrict__ out) {
  __shared__ unsigned short As[128 * 64];
  __shared__ unsigned short Bs[128 * 64];
  const int t = threadIdx.x;
  const int lane = t & 63, wid = t >> 6;
  const int wm = wid >> 1, wn = wid & 1;
  const int m0 = blockIdx.y * 128, n0 = blockIdx.x * 128;
  const int lrow = lane & 15, lgrp = lane >> 4;
  f32x4 acc[4][4] = {};
  for (int kt = 0; kt < HD; kt += 64) {
#pragma unroll
    for (int it = 0; it < 4; ++it) {
      int slot = it * 256 + t;
      int row = slot >> 3, g = slot & 7;
      int sg = g ^ (row & 7);                       // pre-swizzled source
      const unsigned short* sa = Tm + (size_t)(m0 + row) * HD + kt + sg * 8;
      const unsigned short* sb = Wv + (size_t)(n0 + row) * HD + kt + sg * 8;
      unsigned short* da = &As[(it * 256 + wid * 64) * 8];  // wave-uniform base
      unsigned short* db = &Bs[(it * 256 + wid * 64) * 8];
      gl_lds16(sa, da);
      gl_lds16(sb, db);
    }
    __syncthreads();
#pragma unroll
    for (int kk = 0; kk < 2; ++kk) {
      short8 af[4], bfr[4];
#pragma unroll
      for (int i = 0; i < 4; ++i) {
        int row = wm * 64 + i * 16 + lrow;
        int gg = (kk * 4 + lgrp) ^ (row & 7);       // swizzled read
        af[i] = *reinterpret_cast<const short8*>(&As[row * 64 + gg * 8]);
      }
#pragma unroll
      for (int j = 0; j < 4; ++j) {
        int row = wn * 64 + j * 16 + lrow;
        int gg = (kk * 4 + lgrp) ^ (row & 7);
        bfr[j] = *reinterpret_cast<const short8*>(&Bs[row * 64 + gg * 8]);
      }
#pragma unroll
      for (int i = 0; i < 4; ++i)
#pragma unroll
        for (int j = 0; j < 4; ++j)
          acc[i][j] = __builtin_amdgcn_mfma_f32_16x16x32_bf16(af[i], bfr[j], acc[i][j], 0, 0, 0);
    }
    __syncthreads();
  }
#pragma unroll
  for (int j = 0; j < 4; ++j) {
    int col = n0 + wn * 64 + j * 16 + lrow;
    bool cok = col < VOC;
    float bv = cok ? bvoc[col] : 0.f;
#pragma unroll
    for (int i = 0; i < 4; ++i) {
      int rbase = m0 + wm * 64 + i * 16 + lgrp * 4;
#pragma unroll
      for (int e = 0; e < 4; ++e) {
        int row = rbase + e;
        if (cok && row < MROWS) out[(size_t)row * VOC + col] = acc[i][j][e] + bv;
      }
    }
  }
}

extern "C" void kernel_launch(void* const* d_in, const int* in_sizes, int n_in,
                              void* d_out, int out_size, void* d_ws, size_t ws_size,
                              hipStream_t stream) {
  (void)in_sizes; (void)n_in; (void)out_size; (void)ws_size;
  const float* cls  = (const float*)d_in[0];
  const float* Wih  = (const float*)d_in[1];
  const float* Whh  = (const float*)d_in[2];
  const float* bih  = (const float*)d_in[3];
  const float* bhh  = (const float*)d_in[4];
  const float* Wd   = (const float*)d_in[5];
  const float* bd   = (const float*)d_in[6];
  const float* gmm  = (const float*)d_in[7];
  const float* bet  = (const float*)d_in[8];
  const float* Wv   = (const float*)d_in[9];
  const float* bvoc = (const float*)d_in[10];
  char* ws = (char*)d_ws;
  int*   bar  = (int*)(ws);
  float* hbuf = (float*)(ws + OFF_HBUF);
  float* Hall = (float*)(ws + OFF_HALL);
  float* WdT  = (float*)(ws + OFF_WDT);
  unsigned short* Tm  = (unsigned short*)(ws + OFF_T);
  unsigned short* WvB = (unsigned short*)(ws + OFF_WV);
  float* out = (float*)d_out;

  hipLaunchKernelGGL(prep_kernel, dim3(4096), dim3(256), 0, stream, Wd, WdT, Wv, WvB, bar);
  hipLaunchKernelGGL(lstm_kernel, dim3(NBL), dim3(256), 0, stream,
                     cls, Wih, Whh, bih, bhh, hbuf, Hall, bar);
  hipLaunchKernelGGL(head_kernel, dim3(MPAD / 16), dim3(256), 0, stream,
                     Hall, WdT, bd, gmm, bet, Tm);
  hipLaunchKernelGGL(gemm_kernel, dim3(VOCP / 128, MPAD / 128), dim3(256), 0, stream,
                     Tm, WvB, bvoc, out);
}

// Round 2
// 10618.436 us; speedup vs baseline: 1.8468x; 1.8468x over previous
//
#include <hip/hip_runtime.h>
#include <hip/hip_bf16.h>
#include <cstdint>

#define HD 768
#define VOC 21128
#define VOCP 21248
#define NSTEPS 511
#define MROWS 4088      // 511*8
#define MPAD 4096
#define NBL 192         // lstm blocks (co-resident, 192 < 256 CUs)

typedef float f32x4 __attribute__((ext_vector_type(4)));
typedef short short8 __attribute__((ext_vector_type(8)));

// ---- workspace layout (bytes) ----
// 0        : flags[192] int (monotone per-block step counters)      (768)
// 768      : hbuf[2][192][32] f32  packed h slices, 128B/block      (49152)
// 49920    : Hall[4088][768] f32 (head may read 8 junk rows beyond;
//            they land in WdT region -> finite floats, harmless)    (12558336)
// 12632576 : WdT[768][768] f32                                      (2359296)
// 14991872 : T[4096][768] bf16                                      (6291456)
// 21283328 : WvB[21248][768] bf16                                   (32636928) -> end 53920256
#define OFF_HBUF 768
#define OFF_HALL 49920
#define OFF_WDT  12632576ULL
#define OFF_T    14991872ULL
#define OFF_WV   21283328ULL
#define PADH 772        // h_lds row stride (bank-conflict pad)

__device__ __forceinline__ unsigned short f2bf(float x) {
  unsigned u = __float_as_uint(x);
  u += 0x7FFFu + ((u >> 16) & 1u);   // RNE
  return (unsigned short)(u >> 16);
}

__device__ __forceinline__ void gl_lds16(const void* g, void* l) {
  __builtin_amdgcn_global_load_lds(
      (const __attribute__((address_space(1))) void*)g,
      (__attribute__((address_space(3))) void*)l, 16, 0, 0);
}

// ---------------- prep: WdT transpose, Wv->bf16 (padded), flags zero ------
__global__ __launch_bounds__(256) void prep_kernel(
    const float* __restrict__ Wd, float* __restrict__ WdT,
    const float* __restrict__ Wv, unsigned short* __restrict__ WvB,
    int* __restrict__ flags) {
  unsigned idx = blockIdx.x * 256 + threadIdx.x;
  if (idx < NBL) flags[idx] = 0;
  unsigned stride = gridDim.x * 256;
  for (unsigned i = idx; i < HD * HD; i += stride) {
    unsigned k = i / HD, j = i - k * HD;
    WdT[i] = Wd[j * HD + k];           // WdT[k][j] = Wd[j][k]
  }
  const unsigned NV = (unsigned)VOCP * HD, NVr = (unsigned)VOC * HD;
  for (unsigned i = idx; i < NV; i += stride)
    WvB[i] = f2bf(i < NVr ? Wv[i] : 0.f);
}

// ---------------- lstm: persistent, 192 blocks, flag-wave sync per step ----
__global__ __launch_bounds__(256) void lstm_kernel(
    const float* __restrict__ cls, const float* __restrict__ Wih,
    const float* __restrict__ Whh, const float* __restrict__ bih,
    const float* __restrict__ bhh, float* __restrict__ hbuf,
    float* __restrict__ Hall, int* __restrict__ flags) {
  __shared__ float h_lds[8 * PADH];    // current h (or cls), [b][k] padded
  __shared__ float red[4][16][8];      // per-wave partial sums
  __shared__ float gval[16][8];        // final gate values
  const int t = threadIdx.x;
  const int blk = blockIdx.x;
  const int p_ = t & 7;                // row-pair 0..7 (16 rows/block)
  const int s_ = t >> 3;               // k-slice 0..31 (24 k each)
  const int ks = s_ * 24;
  const int r0 = 2 * p_, r1 = r0 + 1;  // local rows; gate=r>>2, unit=r&3
  const int grow0 = (r0 >> 2) * HD + blk * 4 + (r0 & 3);
  const int grow1 = (r1 >> 2) * HD + blk * 4 + (r1 & 3);
  float w0[24], w1[24];
#pragma unroll
  for (int j = 0; j < 24; ++j) {
    w0[j] = Wih[(size_t)grow0 * HD + ks + j];
    w1[j] = Wih[(size_t)grow1 * HD + ks + j];
  }
  float bias = 0.f;
  if (t < 128) {
    int r = t >> 3;
    int gr = (r >> 2) * HD + blk * 4 + (r & 3);
    bias = bih[gr] + bhh[gr];
  }
  float cstate = 0.f;

  // hout_slice: this block's 32-float slice (layout [b*4+ul]); hall_row: [b][768]
  auto do_step = [&](float* __restrict__ hout_slice, float* __restrict__ hall_row) {
    float acc0[8], acc1[8];
#pragma unroll
    for (int b = 0; b < 8; ++b) { acc0[b] = 0.f; acc1[b] = 0.f; }
#pragma unroll
    for (int b = 0; b < 8; ++b) {
      const float* hb = &h_lds[b * PADH + ks];
#pragma unroll
      for (int j4 = 0; j4 < 6; ++j4) {
        f32x4 hv = *reinterpret_cast<const f32x4*>(hb + j4 * 4);
#pragma unroll
        for (int e = 0; e < 4; ++e) {
          acc0[b] = fmaf(w0[j4 * 4 + e], hv[e], acc0[b]);
          acc1[b] = fmaf(w1[j4 * 4 + e], hv[e], acc1[b]);
        }
      }
    }
#pragma unroll
    for (int b = 0; b < 8; ++b) {   // reduce over the wave's 8 k-slices
      acc0[b] += __shfl_xor(acc0[b], 8);
      acc0[b] += __shfl_xor(acc0[b], 16);
      acc0[b] += __shfl_xor(acc0[b], 32);
      acc1[b] += __shfl_xor(acc1[b], 8);
      acc1[b] += __shfl_xor(acc1[b], 16);
      acc1[b] += __shfl_xor(acc1[b], 32);
    }
    const int lane = t & 63, wv = t >> 6;
    if (lane < 8) {
#pragma unroll
      for (int b = 0; b < 8; ++b) {
        red[wv][2 * lane][b] = acc0[b];
        red[wv][2 * lane + 1][b] = acc1[b];
      }
    }
    __syncthreads();
    if (t < 128) {
      int r = t >> 3, b = t & 7;
      gval[r][b] = red[0][r][b] + red[1][r][b] + red[2][r][b] + red[3][r][b] + bias;
    }
    __syncthreads();
    if (t < 32) {
      int ul = t >> 3, b = t & 7;
      float gi = gval[ul][b], gf = gval[4 + ul][b];
      float gg = gval[8 + ul][b], go = gval[12 + ul][b];
      float iv = 1.f / (1.f + expf(-gi));
      float fv = 1.f / (1.f + expf(-gf));
      float gv = tanhf(gg);
      float ov = 1.f / (1.f + expf(-go));
      cstate = fv * cstate + iv * gv;
      float hn = ov * tanhf(cstate);
      hout_slice[b * 4 + ul] = hn;
      if (hall_row) hall_row[(size_t)b * HD + blk * 4 + ul] = hn;
    }
  };

  // pre-step: h1 = cell(cls, 0, 0) -> gates = cls@Wih^T + (bih+bhh)
  for (int i = t; i < 1536; i += 256) {
    int b = i / 192, c4 = i - b * 192;
    *reinterpret_cast<f32x4*>(&h_lds[b * PADH + c4 * 4]) =
        reinterpret_cast<const f32x4*>(cls)[i];
  }
  __syncthreads();
  do_step(hbuf + 6144 + blk * 32, nullptr);    // h_1 -> parity 1
  __syncthreads();
  if (t == 0) {
    __threadfence();
    __hip_atomic_store(&flags[blk], 1, __ATOMIC_RELEASE, __HIP_MEMORY_SCOPE_AGENT);
  }
  // switch to combined weights W_ih + W_hh (inside the scan, x == h)
#pragma unroll
  for (int j = 0; j < 24; ++j) {
    w0[j] += Whh[(size_t)grow0 * HD + ks + j];
    w1[j] += Whh[(size_t)grow1 * HD + ks + j];
  }
  for (int s = 1; s <= NSTEPS; ++s) {
    if (t < NBL) {
      // wait until every block has published h_s
      while (__hip_atomic_load(&flags[t], __ATOMIC_ACQUIRE, __HIP_MEMORY_SCOPE_AGENT) < s)
        __builtin_amdgcn_s_sleep(1);
      // gather h_s: vec4 slot i -> src block i>>3, batch i&7
      const f32x4* src = reinterpret_cast<const f32x4*>(hbuf + (s & 1) * 6144);
#pragma unroll
      for (int k = 0; k < 8; ++k) {
        int i = t + k * NBL;               // 0..1535
        f32x4 v = src[i];
        *reinterpret_cast<f32x4*>(&h_lds[(i & 7) * PADH + (i >> 3) * 4]) = v;
      }
    }
    __syncthreads();
    do_step(hbuf + ((s + 1) & 1) * 6144 + blk * 32,
            Hall + (size_t)(s - 1) * (8 * HD));
    __syncthreads();
    if (t == 0) {
      __threadfence();   // single wbl2: flush this block's h slice + Hall row
      __hip_atomic_store(&flags[blk], s + 1, __ATOMIC_RELEASE, __HIP_MEMORY_SCOPE_AGENT);
    }
  }
}

// ---------------- head: dense + gelu(erf) + LayerNorm -> T (bf16) ----------
__global__ __launch_bounds__(256) void head_kernel(
    const float* __restrict__ Hall, const float* __restrict__ WdT,
    const float* __restrict__ bd, const float* __restrict__ gamma,
    const float* __restrict__ beta, unsigned short* __restrict__ Tm) {
  __shared__ float hT[HD][16];
  __shared__ float rbuf[4][16];
  __shared__ float mu_s[16], rs_s[16];
  const int t = threadIdx.x;
  const int r0 = blockIdx.x * 16;
  {
    const int row = t & 15, ksl = t >> 4;
    const float* src = Hall + (size_t)(r0 + row) * HD + ksl * 48;
#pragma unroll
    for (int i = 0; i < 12; ++i) {
      f32x4 v = *reinterpret_cast<const f32x4*>(src + i * 4);
      int k = ksl * 48 + i * 4;
      hT[k][row] = v[0]; hT[k + 1][row] = v[1];
      hT[k + 2][row] = v[2]; hT[k + 3][row] = v[3];
    }
  }
  __syncthreads();
  float a0[16], a1[16], a2[16];
#pragma unroll
  for (int r = 0; r < 16; ++r) { a0[r] = 0.f; a1[r] = 0.f; a2[r] = 0.f; }
  for (int k = 0; k < HD; ++k) {
    float wa = WdT[(size_t)k * HD + t];
    float wb = WdT[(size_t)k * HD + t + 256];
    float wc = WdT[(size_t)k * HD + t + 512];
    f32x4 hv4[4];
#pragma unroll
    for (int q = 0; q < 4; ++q)
      hv4[q] = *reinterpret_cast<const f32x4*>(&hT[k][q * 4]);
#pragma unroll
    for (int r = 0; r < 16; ++r) {
      float hv = hv4[r >> 2][r & 3];
      a0[r] = fmaf(wa, hv, a0[r]);
      a1[r] = fmaf(wb, hv, a1[r]);
      a2[r] = fmaf(wc, hv, a2[r]);
    }
  }
  float g0 = gamma[t], g1 = gamma[t + 256], g2 = gamma[t + 512];
  float be0 = beta[t], be1 = beta[t + 256], be2 = beta[t + 512];
  float bd0 = bd[t], bd1 = bd[t + 256], bd2 = bd[t + 512];
#pragma unroll
  for (int r = 0; r < 16; ++r) {
    float x;
    x = a0[r] + bd0; a0[r] = 0.5f * x * (1.f + erff(x * 0.7071067811865476f));
    x = a1[r] + bd1; a1[r] = 0.5f * x * (1.f + erff(x * 0.7071067811865476f));
    x = a2[r] + bd2; a2[r] = 0.5f * x * (1.f + erff(x * 0.7071067811865476f));
  }
  float ps[16];
  const int lane = t & 63, wv = t >> 6;
#pragma unroll
  for (int r = 0; r < 16; ++r) ps[r] = a0[r] + a1[r] + a2[r];
#pragma unroll
  for (int r = 0; r < 16; ++r)
#pragma unroll
    for (int m = 1; m < 64; m <<= 1) ps[r] += __shfl_xor(ps[r], m);
  if (lane == 0) {
#pragma unroll
    for (int r = 0; r < 16; ++r) rbuf[wv][r] = ps[r];
  }
  __syncthreads();
  if (t < 16) mu_s[t] = (rbuf[0][t] + rbuf[1][t] + rbuf[2][t] + rbuf[3][t]) * (1.f / HD);
  __syncthreads();
#pragma unroll
  for (int r = 0; r < 16; ++r) {
    float mu = mu_s[r];
    float d0 = a0[r] - mu, d1 = a1[r] - mu, d2 = a2[r] - mu;
    ps[r] = d0 * d0 + d1 * d1 + d2 * d2;
  }
#pragma unroll
  for (int r = 0; r < 16; ++r)
#pragma unroll
    for (int m = 1; m < 64; m <<= 1) ps[r] += __shfl_xor(ps[r], m);
  if (lane == 0) {
#pragma unroll
    for (int r = 0; r < 16; ++r) rbuf[wv][r] = ps[r];
  }
  __syncthreads();
  if (t < 16)
    rs_s[t] = 1.f / sqrtf((rbuf[0][t] + rbuf[1][t] + rbuf[2][t] + rbuf[3][t]) * (1.f / HD) + 1e-12f);
  __syncthreads();
#pragma unroll
  for (int r = 0; r < 16; ++r) {
    float mu = mu_s[r], rs = rs_s[r];
    size_t ro = (size_t)(r0 + r) * HD;
    Tm[ro + t]       = f2bf((a0[r] - mu) * rs * g0 + be0);
    Tm[ro + t + 256] = f2bf((a1[r] - mu) * rs * g1 + be1);
    Tm[ro + t + 512] = f2bf((a2[r] - mu) * rs * g2 + be2);
  }
}

// ---------------- decoder GEMM: out = T @ WvB^T + bvoc  (bf16 MFMA) -------
__global__ __launch_bounds__(256) void gemm_kernel(
    const unsigned short* __restrict__ Tm, const unsigned short* __restrict__ Wv,
    const float* __restrict__ bvoc, float* __restrict__ out) {
  __shared__ unsigned short As[128 * 64];
  __shared__ unsigned short Bs[128 * 64];
  const int t = threadIdx.x;
  const int lane = t & 63, wid = t >> 6;
  const int wm = wid >> 1, wn = wid & 1;
  const int m0 = blockIdx.y * 128, n0 = blockIdx.x * 128;
  const int lrow = lane & 15, lgrp = lane >> 4;
  f32x4 acc[4][4] = {};
  for (int kt = 0; kt < HD; kt += 64) {
#pragma unroll
    for (int it = 0; it < 4; ++it) {
      int slot = it * 256 + t;
      int row = slot >> 3, g = slot & 7;
      int sg = g ^ (row & 7);                       // pre-swizzled source
      const unsigned short* sa = Tm + (size_t)(m0 + row) * HD + kt + sg * 8;
      const unsigned short* sb = Wv + (size_t)(n0 + row) * HD + kt + sg * 8;
      unsigned short* da = &As[(it * 256 + wid * 64) * 8];  // wave-uniform base
      unsigned short* db = &Bs[(it * 256 + wid * 64) * 8];
      gl_lds16(sa, da);
      gl_lds16(sb, db);
    }
    __syncthreads();
#pragma unroll
    for (int kk = 0; kk < 2; ++kk) {
      short8 af[4], bfr[4];
#pragma unroll
      for (int i = 0; i < 4; ++i) {
        int row = wm * 64 + i * 16 + lrow;
        int gg = (kk * 4 + lgrp) ^ (row & 7);       // swizzled read
        af[i] = *reinterpret_cast<const short8*>(&As[row * 64 + gg * 8]);
      }
#pragma unroll
      for (int j = 0; j < 4; ++j) {
        int row = wn * 64 + j * 16 + lrow;
        int gg = (kk * 4 + lgrp) ^ (row & 7);
        bfr[j] = *reinterpret_cast<const short8*>(&Bs[row * 64 + gg * 8]);
      }
#pragma unroll
      for (int i = 0; i < 4; ++i)
#pragma unroll
        for (int j = 0; j < 4; ++j)
          acc[i][j] = __builtin_amdgcn_mfma_f32_16x16x32_bf16(af[i], bfr[j], acc[i][j], 0, 0, 0);
    }
    __syncthreads();
  }
#pragma unroll
  for (int j = 0; j < 4; ++j) {
    int col = n0 + wn * 64 + j * 16 + lrow;
    bool cok = col < VOC;
    float bv = cok ? bvoc[col] : 0.f;
#pragma unroll
    for (int i = 0; i < 4; ++i) {
      int rbase = m0 + wm * 64 + i * 16 + lgrp * 4;
#pragma unroll
      for (int e = 0; e < 4; ++e) {
        int row = rbase + e;
        if (cok && row < MROWS) out[(size_t)row * VOC + col] = acc[i][j][e] + bv;
      }
    }
  }
}

extern "C" void kernel_launch(void* const* d_in, const int* in_sizes, int n_in,
                              void* d_out, int out_size, void* d_ws, size_t ws_size,
                              hipStream_t stream) {
  (void)in_sizes; (void)n_in; (void)out_size; (void)ws_size;
  const float* cls  = (const float*)d_in[0];
  const float* Wih  = (const float*)d_in[1];
  const float* Whh  = (const float*)d_in[2];
  const float* bih  = (const float*)d_in[3];
  const float* bhh  = (const float*)d_in[4];
  const float* Wd   = (const float*)d_in[5];
  const float* bd   = (const float*)d_in[6];
  const float* gmm  = (const float*)d_in[7];
  const float* bet  = (const float*)d_in[8];
  const float* Wv   = (const float*)d_in[9];
  const float* bvoc = (const float*)d_in[10];
  char* ws = (char*)d_ws;
  int*   flags = (int*)(ws);
  float* hbuf  = (float*)(ws + OFF_HBUF);
  float* Hall  = (float*)(ws + OFF_HALL);
  float* WdT   = (float*)(ws + OFF_WDT);
  unsigned short* Tm  = (unsigned short*)(ws + OFF_T);
  unsigned short* WvB = (unsigned short*)(ws + OFF_WV);
  float* out = (float*)d_out;

  hipLaunchKernelGGL(prep_kernel, dim3(4096), dim3(256), 0, stream, Wd, WdT, Wv, WvB, flags);
  hipLaunchKernelGGL(lstm_kernel, dim3(NBL), dim3(256), 0, stream,
                     cls, Wih, Whh, bih, bhh, hbuf, Hall, flags);
  hipLaunchKernelGGL(head_kernel, dim3(MPAD / 16), dim3(256), 0, stream,
                     Hall, WdT, bd, gmm, bet, Tm);
  hipLaunchKernelGGL(gemm_kernel, dim3(VOCP / 128, MPAD / 128), dim3(256), 0, stream,
                     Tm, WvB, bvoc, out);
}

// Round 5
// 7752.747 us; speedup vs baseline: 2.5294x; 1.3696x over previous
//
#include <hip/hip_runtime.h>
#include <hip/hip_bf16.h>
#include <cstdint>

#define HD 768
#define VOC 21128
#define VOCP 21248
#define NSTEPS 511
#define MROWS 4088      // 511*8
#define MPAD 4096
#define NBL 192         // lstm blocks (co-resident, 192 < 256 CUs)

typedef float f32x4 __attribute__((ext_vector_type(4)));
typedef short short8 __attribute__((ext_vector_type(8)));

// ---- workspace layout (bytes) ----
// 0        : flags[192] int (monotone per-block step counters)      (768)
// 768      : hbuf[2][192][32] f32  packed h slices, 128B/block      (49152)
// 49920    : Hall[4088][768] f32                                    (12558336)
// 12632576 : WdT[768][768] f32                                      (2359296)
// 14991872 : T[4096][768] bf16                                      (6291456)
// 21283328 : WvB[21248][768] bf16                                   (32636928) -> end 53920256
#define OFF_HBUF 768
#define OFF_HALL 49920
#define OFF_WDT  12632576ULL
#define OFF_T    14991872ULL
#define OFF_WV   21283328ULL
#define PADH 772        // h_lds row stride (bank-conflict pad)

__device__ __forceinline__ unsigned short f2bf(float x) {
  unsigned u = __float_as_uint(x);
  u += 0x7FFFu + ((u >> 16) & 1u);   // RNE
  return (unsigned short)(u >> 16);
}

__device__ __forceinline__ void gl_lds16(const void* g, void* l) {
  __builtin_amdgcn_global_load_lds(
      (const __attribute__((address_space(1))) void*)g,
      (__attribute__((address_space(3))) void*)l, 16, 0, 0);
}

// relaxed agent-scope (sc1) accesses: coherent-point traffic, no cache-wide ops
__device__ __forceinline__ void st_wt(float* p, float v) {
  __hip_atomic_store(p, v, __ATOMIC_RELAXED, __HIP_MEMORY_SCOPE_AGENT);
}

// ---------------- prep: WdT transpose, Wv->bf16 (padded), flags zero ------
__global__ __launch_bounds__(256) void prep_kernel(
    const float* __restrict__ Wd, float* __restrict__ WdT,
    const float* __restrict__ Wv, unsigned short* __restrict__ WvB,
    int* __restrict__ flags) {
  unsigned idx = blockIdx.x * 256 + threadIdx.x;
  if (idx < NBL) flags[idx] = 0;
  unsigned stride = gridDim.x * 256;
  for (unsigned i = idx; i < HD * HD; i += stride) {
    unsigned k = i / HD, j = i - k * HD;
    WdT[i] = Wd[j * HD + k];           // WdT[k][j] = Wd[j][k]
  }
  const unsigned NV = (unsigned)VOCP * HD, NVr = (unsigned)VOC * HD;
  for (unsigned i = idx; i < NV; i += stride)
    WvB[i] = f2bf(i < NVr ? Wv[i] : 0.f);
}

// ---------------- lstm: persistent, 192 blocks, release-flag protocol -----
__global__ __launch_bounds__(256) void lstm_kernel(
    const float* __restrict__ cls, const float* __restrict__ Wih,
    const float* __restrict__ Whh, const float* __restrict__ bih,
    const float* __restrict__ bhh, float* __restrict__ hbuf,
    float* __restrict__ Hall, int* __restrict__ flags) {
  __shared__ float h_lds[8 * PADH];    // current h (or cls), [b][k] padded
  __shared__ float red[4][16][8];      // per-wave partial sums
  __shared__ float gval[16][8];        // final gate values
  const int t = threadIdx.x;
  const int blk = blockIdx.x;
  const int p_ = t & 7;                // row-pair 0..7 (16 rows/block)
  const int s_ = t >> 3;               // k-slice 0..31 (24 k each)
  const int ks = s_ * 24;
  const int r0 = 2 * p_, r1 = r0 + 1;  // local rows; gate=r>>2, unit=r&3
  const int grow0 = (r0 >> 2) * HD + blk * 4 + (r0 & 3);
  const int grow1 = (r1 >> 2) * HD + blk * 4 + (r1 & 3);
  float w0[24], w1[24];
#pragma unroll
  for (int j = 0; j < 24; ++j) {
    w0[j] = Wih[(size_t)grow0 * HD + ks + j];
    w1[j] = Wih[(size_t)grow1 * HD + ks + j];
  }
  float bias = 0.f;
  if (t < 128) {
    int r = t >> 3;
    int gr = (r >> 2) * HD + blk * 4 + (r & 3);
    bias = bih[gr] + bhh[gr];
  }
  float cstate = 0.f;

  // hout_slice: this block's 32-float slice (layout [b*4+ul]); hall_row: [b][768]
  auto do_step = [&](float* __restrict__ hout_slice, float* __restrict__ hall_row) {
    float acc0[8], acc1[8];
#pragma unroll
    for (int b = 0; b < 8; ++b) { acc0[b] = 0.f; acc1[b] = 0.f; }
#pragma unroll
    for (int b = 0; b < 8; ++b) {
      const float* hb = &h_lds[b * PADH + ks];
#pragma unroll
      for (int j4 = 0; j4 < 6; ++j4) {
        f32x4 hv = *reinterpret_cast<const f32x4*>(hb + j4 * 4);
#pragma unroll
        for (int e = 0; e < 4; ++e) {
          acc0[b] = fmaf(w0[j4 * 4 + e], hv[e], acc0[b]);
          acc1[b] = fmaf(w1[j4 * 4 + e], hv[e], acc1[b]);
        }
      }
    }
#pragma unroll
    for (int b = 0; b < 8; ++b) {   // reduce over the wave's 8 k-slices
      acc0[b] += __shfl_xor(acc0[b], 8);
      acc0[b] += __shfl_xor(acc0[b], 16);
      acc0[b] += __shfl_xor(acc0[b], 32);
      acc1[b] += __shfl_xor(acc1[b], 8);
      acc1[b] += __shfl_xor(acc1[b], 16);
      acc1[b] += __shfl_xor(acc1[b], 32);
    }
    const int lane = t & 63, wv = t >> 6;
    if (lane < 8) {
#pragma unroll
      for (int b = 0; b < 8; ++b) {
        red[wv][2 * lane][b] = acc0[b];
        red[wv][2 * lane + 1][b] = acc1[b];
      }
    }
    __syncthreads();
    if (t < 128) {
      int r = t >> 3, b = t & 7;
      gval[r][b] = red[0][r][b] + red[1][r][b] + red[2][r][b] + red[3][r][b] + bias;
    }
    __syncthreads();
    if (t < 32) {
      int ul = t >> 3, b = t & 7;
      float gi = gval[ul][b], gf = gval[4 + ul][b];
      float gg = gval[8 + ul][b], go = gval[12 + ul][b];
      float iv = 1.f / (1.f + expf(-gi));
      float fv = 1.f / (1.f + expf(-gf));
      float gv = tanhf(gg);
      float ov = 1.f / (1.f + expf(-go));
      cstate = fv * cstate + iv * gv;
      float hn = ov * tanhf(cstate);
      st_wt(&hout_slice[b * 4 + ul], hn);        // sc1 write-through
      if (hall_row) hall_row[(size_t)b * HD + blk * 4 + ul] = hn;  // plain
    }
  };

  // proper agent-scope release: compiler emits buffer_wbl2 sc1 + waitcnt + store
  auto publish = [&](int gen) {
    __syncthreads();   // all waves' stores drained (vmcnt(0) before s_barrier)
    if (t == 0)
      __hip_atomic_store(&flags[blk], gen, __ATOMIC_RELEASE, __HIP_MEMORY_SCOPE_AGENT);
  };

  // pre-step: h1 = cell(cls, 0, 0) -> gates = cls@Wih^T + (bih+bhh)
  for (int i = t; i < 1536; i += 256) {
    int b = i / 192, c4 = i - b * 192;
    *reinterpret_cast<f32x4*>(&h_lds[b * PADH + c4 * 4]) =
        reinterpret_cast<const f32x4*>(cls)[i];
  }
  __syncthreads();
  do_step(hbuf + 6144 + blk * 32, nullptr);    // h_1 -> parity 1
  publish(1);
  // switch to combined weights W_ih + W_hh (inside the scan, x == h)
#pragma unroll
  for (int j = 0; j < 24; ++j) {
    w0[j] += Whh[(size_t)grow0 * HD + ks + j];
    w1[j] += Whh[(size_t)grow1 * HD + ks + j];
  }
  for (int s = 1; s <= NSTEPS; ++s) {
    if (t < NBL) {
      // wait until block t has published h_s (relaxed sc1 load, no cache ops)
      while (__hip_atomic_load(&flags[t], __ATOMIC_RELAXED, __HIP_MEMORY_SCOPE_AGENT) < s)
        __builtin_amdgcn_s_sleep(1);
    }
    __syncthreads();   // all 192 flags confirmed by someone in this block
    __builtin_amdgcn_fence(__ATOMIC_ACQUIRE, "agent");  // one inv/wave/step
    {
      // gather h_s: 256 threads x 6 f32x4 = 6144 floats (FULL buffer).
      // f32x4 slot i: src block = i>>3, batch = i&7 (slice layout [b*4+ul]).
      const f32x4* src = reinterpret_cast<const f32x4*>(hbuf + (s & 1) * 6144);
#pragma unroll
      for (int k = 0; k < 6; ++k) {
        int i = t + k * 256;               // 0..1535 vec4 slots
        f32x4 v = src[i];
        *reinterpret_cast<f32x4*>(&h_lds[(i & 7) * PADH + (i >> 3) * 4]) = v;
      }
    }
    __syncthreads();
    do_step(hbuf + ((s + 1) & 1) * 6144 + blk * 32,
            Hall + (size_t)(s - 1) * (8 * HD));
    publish(s + 1);
  }
}

// ---------------- head: dense + gelu(erf) + LayerNorm -> T (bf16) ----------
__global__ __launch_bounds__(256) void head_kernel(
    const float* __restrict__ Hall, const float* __restrict__ WdT,
    const float* __restrict__ bd, const float* __restrict__ gamma,
    const float* __restrict__ beta, unsigned short* __restrict__ Tm) {
  __shared__ float hT[HD][16];
  __shared__ float rbuf[4][16];
  __shared__ float mu_s[16], rs_s[16];
  const int t = threadIdx.x;
  const int r0 = blockIdx.x * 16;
  {
    const int row = t & 15, ksl = t >> 4;
    const float* src = Hall + (size_t)(r0 + row) * HD + ksl * 48;
#pragma unroll
    for (int i = 0; i < 12; ++i) {
      f32x4 v = *reinterpret_cast<const f32x4*>(src + i * 4);
      int k = ksl * 48 + i * 4;
      hT[k][row] = v[0]; hT[k + 1][row] = v[1];
      hT[k + 2][row] = v[2]; hT[k + 3][row] = v[3];
    }
  }
  __syncthreads();
  float a0[16], a1[16], a2[16];
#pragma unroll
  for (int r = 0; r < 16; ++r) { a0[r] = 0.f; a1[r] = 0.f; a2[r] = 0.f; }
  for (int k = 0; k < HD; ++k) {
    float wa = WdT[(size_t)k * HD + t];
    float wb = WdT[(size_t)k * HD + t + 256];
    float wc = WdT[(size_t)k * HD + t + 512];
    f32x4 hv4[4];
#pragma unroll
    for (int q = 0; q < 4; ++q)
      hv4[q] = *reinterpret_cast<const f32x4*>(&hT[k][q * 4]);
#pragma unroll
    for (int r = 0; r < 16; ++r) {
      float hv = hv4[r >> 2][r & 3];
      a0[r] = fmaf(wa, hv, a0[r]);
      a1[r] = fmaf(wb, hv, a1[r]);
      a2[r] = fmaf(wc, hv, a2[r]);
    }
  }
  float g0 = gamma[t], g1 = gamma[t + 256], g2 = gamma[t + 512];
  float be0 = beta[t], be1 = beta[t + 256], be2 = beta[t + 512];
  float bd0 = bd[t], bd1 = bd[t + 256], bd2 = bd[t + 512];
#pragma unroll
  for (int r = 0; r < 16; ++r) {
    float x;
    x = a0[r] + bd0; a0[r] = 0.5f * x * (1.f + erff(x * 0.7071067811865476f));
    x = a1[r] + bd1; a1[r] = 0.5f * x * (1.f + erff(x * 0.7071067811865476f));
    x = a2[r] + bd2; a2[r] = 0.5f * x * (1.f + erff(x * 0.7071067811865476f));
  }
  float ps[16];
  const int lane = t & 63, wv = t >> 6;
#pragma unroll
  for (int r = 0; r < 16; ++r) ps[r] = a0[r] + a1[r] + a2[r];
#pragma unroll
  for (int r = 0; r < 16; ++r)
#pragma unroll
    for (int m = 1; m < 64; m <<= 1) ps[r] += __shfl_xor(ps[r], m);
  if (lane == 0) {
#pragma unroll
    for (int r = 0; r < 16; ++r) rbuf[wv][r] = ps[r];
  }
  __syncthreads();
  if (t < 16) mu_s[t] = (rbuf[0][t] + rbuf[1][t] + rbuf[2][t] + rbuf[3][t]) * (1.f / HD);
  __syncthreads();
#pragma unroll
  for (int r = 0; r < 16; ++r) {
    float mu = mu_s[r];
    float d0 = a0[r] - mu, d1 = a1[r] - mu, d2 = a2[r] - mu;
    ps[r] = d0 * d0 + d1 * d1 + d2 * d2;
  }
#pragma unroll
  for (int r = 0; r < 16; ++r)
#pragma unroll
    for (int m = 1; m < 64; m <<= 1) ps[r] += __shfl_xor(ps[r], m);
  if (lane == 0) {
#pragma unroll
    for (int r = 0; r < 16; ++r) rbuf[wv][r] = ps[r];
  }
  __syncthreads();
  if (t < 16)
    rs_s[t] = 1.f / sqrtf((rbuf[0][t] + rbuf[1][t] + rbuf[2][t] + rbuf[3][t]) * (1.f / HD) + 1e-12f);
  __syncthreads();
#pragma unroll
  for (int r = 0; r < 16; ++r) {
    float mu = mu_s[r], rs = rs_s[r];
    size_t ro = (size_t)(r0 + r) * HD;
    Tm[ro + t]       = f2bf((a0[r] - mu) * rs * g0 + be0);
    Tm[ro + t + 256] = f2bf((a1[r] - mu) * rs * g1 + be1);
    Tm[ro + t + 512] = f2bf((a2[r] - mu) * rs * g2 + be2);
  }
}

// ---------------- decoder GEMM: out = T @ WvB^T + bvoc  (bf16 MFMA) -------
__global__ __launch_bounds__(256) void gemm_kernel(
    const unsigned short* __restrict__ Tm, const unsigned short* __restrict__ Wv,
    const float* __restrict__ bvoc, float* __restrict__ out) {
  __shared__ unsigned short As[128 * 64];
  __shared__ unsigned short Bs[128 * 64];
  const int t = threadIdx.x;
  const int lane = t & 63, wid = t >> 6;
  const int wm = wid >> 1, wn = wid & 1;
  const int m0 = blockIdx.y * 128, n0 = blockIdx.x * 128;
  const int lrow = lane & 15, lgrp = lane >> 4;
  f32x4 acc[4][4] = {};
  for (int kt = 0; kt < HD; kt += 64) {
#pragma unroll
    for (int it = 0; it < 4; ++it) {
      int slot = it * 256 + t;
      int row = slot >> 3, g = slot & 7;
      int sg = g ^ (row & 7);                       // pre-swizzled source
      const unsigned short* sa = Tm + (size_t)(m0 + row) * HD + kt + sg * 8;
      const unsigned short* sb = Wv + (size_t)(n0 + row) * HD + kt + sg * 8;
      unsigned short* da = &As[(it * 256 + wid * 64) * 8];  // wave-uniform base
      unsigned short* db = &Bs[(it * 256 + wid * 64) * 8];
      gl_lds16(sa, da);
      gl_lds16(sb, db);
    }
    __syncthreads();
#pragma unroll
    for (int kk = 0; kk < 2; ++kk) {
      short8 af[4], bfr[4];
#pragma unroll
      for (int i = 0; i < 4; ++i) {
        int row = wm * 64 + i * 16 + lrow;
        int gg = (kk * 4 + lgrp) ^ (row & 7);       // swizzled read
        af[i] = *reinterpret_cast<const short8*>(&As[row * 64 + gg * 8]);
      }
#pragma unroll
      for (int j = 0; j < 4; ++j) {
        int row = wn * 64 + j * 16 + lrow;
        int gg = (kk * 4 + lgrp) ^ (row & 7);
        bfr[j] = *reinterpret_cast<const short8*>(&Bs[row * 64 + gg * 8]);
      }
#pragma unroll
      for (int i = 0; i < 4; ++i)
#pragma unroll
        for (int j = 0; j < 4; ++j)
          acc[i][j] = __builtin_amdgcn_mfma_f32_16x16x32_bf16(af[i], bfr[j], acc[i][j], 0, 0, 0);
    }
    __syncthreads();
  }
#pragma unroll
  for (int j = 0; j < 4; ++j) {
    int col = n0 + wn * 64 + j * 16 + lrow;
    bool cok = col < VOC;
    float bv = cok ? bvoc[col] : 0.f;
#pragma unroll
    for (int i = 0; i < 4; ++i) {
      int rbase = m0 + wm * 64 + i * 16 + lgrp * 4;
#pragma unroll
      for (int e = 0; e < 4; ++e) {
        int row = rbase + e;
        if (cok && row < MROWS) out[(size_t)row * VOC + col] = acc[i][j][e] + bv;
      }
    }
  }
}

extern "C" void kernel_launch(void* const* d_in, const int* in_sizes, int n_in,
                              void* d_out, int out_size, void* d_ws, size_t ws_size,
                              hipStream_t stream) {
  (void)in_sizes; (void)n_in; (void)out_size; (void)ws_size;
  const float* cls  = (const float*)d_in[0];
  const float* Wih  = (const float*)d_in[1];
  const float* Whh  = (const float*)d_in[2];
  const float* bih  = (const float*)d_in[3];
  const float* bhh  = (const float*)d_in[4];
  const float* Wd   = (const float*)d_in[5];
  const float* bd   = (const float*)d_in[6];
  const float* gmm  = (const float*)d_in[7];
  const float* bet  = (const float*)d_in[8];
  const float* Wv   = (const float*)d_in[9];
  const float* bvoc = (const float*)d_in[10];
  char* ws = (char*)d_ws;
  int*   flags = (int*)(ws);
  float* hbuf  = (float*)(ws + OFF_HBUF);
  float* Hall  = (float*)(ws + OFF_HALL);
  float* WdT   = (float*)(ws + OFF_WDT);
  unsigned short* Tm  = (unsigned short*)(ws + OFF_T);
  unsigned short* WvB = (unsigned short*)(ws + OFF_WV);
  float* out = (float*)d_out;

  hipLaunchKernelGGL(prep_kernel, dim3(4096), dim3(256), 0, stream, Wd, WdT, Wv, WvB, flags);
  hipLaunchKernelGGL(lstm_kernel, dim3(NBL), dim3(256), 0, stream,
                     cls, Wih, Whh, bih, bhh, hbuf, Hall, flags);
  hipLaunchKernelGGL(head_kernel, dim3(MPAD / 16), dim3(256), 0, stream,
                     Hall, WdT, bd, gmm, bet, Tm);
  hipLaunchKernelGGL(gemm_kernel, dim3(VOCP / 128, MPAD / 128), dim3(256), 0, stream,
                     Tm, WvB, bvoc, out);
}

// Round 6
// 3670.084 us; speedup vs baseline: 5.3431x; 2.1124x over previous
//
#include <hip/hip_runtime.h>
#include <hip/hip_bf16.h>
#include <cstdint>

#define HD 768
#define VOC 21128
#define VOCP 21248
#define NSTEPS 511
#define MROWS 4088      // 511*8
#define MPAD 4096
#define NBL 192         // lstm blocks (co-resident, 192 < 256 CUs)

typedef float f32x4 __attribute__((ext_vector_type(4)));
typedef short short8 __attribute__((ext_vector_type(8)));

// ---- workspace layout (bytes) ----
// 0        : flags[192] int (monotone per-block step counters)      (768)
// 768      : hbuf[2][192][32] f32  packed h slices, 128B/block      (49152)
// 49920    : Hall[4088][768] f32                                    (12558336)
// 12632576 : WdT[768][768] f32                                      (2359296)
// 14991872 : T[4096][768] bf16                                      (6291456)
// 21283328 : WvB[21248][768] bf16                                   (32636928) -> end 53920256
#define OFF_HBUF 768
#define OFF_HALL 49920
#define OFF_WDT  12632576ULL
#define OFF_T    14991872ULL
#define OFF_WV   21283328ULL
#define PADH 772        // h_lds row stride (bank-conflict pad)

__device__ __forceinline__ unsigned short f2bf(float x) {
  unsigned u = __float_as_uint(x);
  u += 0x7FFFu + ((u >> 16) & 1u);   // RNE
  return (unsigned short)(u >> 16);
}

__device__ __forceinline__ void gl_lds16(const void* g, void* l) {
  __builtin_amdgcn_global_load_lds(
      (const __attribute__((address_space(1))) void*)g,
      (__attribute__((address_space(3))) void*)l, 16, 0, 0);
}

// relaxed agent-scope (sc1) accesses: coherent-point traffic, no cache-wide ops
__device__ __forceinline__ void st_wt(float* p, float v) {
  __hip_atomic_store(p, v, __ATOMIC_RELAXED, __HIP_MEMORY_SCOPE_AGENT);
}
__device__ __forceinline__ float ld_wt(const float* p) {
  return __hip_atomic_load(p, __ATOMIC_RELAXED, __HIP_MEMORY_SCOPE_AGENT);
}

// ---------------- prep: WdT transpose, Wv->bf16 (padded), flags zero ------
__global__ __launch_bounds__(256) void prep_kernel(
    const float* __restrict__ Wd, float* __restrict__ WdT,
    const float* __restrict__ Wv, unsigned short* __restrict__ WvB,
    int* __restrict__ flags) {
  unsigned idx = blockIdx.x * 256 + threadIdx.x;
  if (idx < NBL) flags[idx] = 0;
  unsigned stride = gridDim.x * 256;
  for (unsigned i = idx; i < HD * HD; i += stride) {
    unsigned k = i / HD, j = i - k * HD;
    WdT[i] = Wd[j * HD + k];           // WdT[k][j] = Wd[j][k]
  }
  const unsigned NV = (unsigned)VOCP * HD, NVr = (unsigned)VOC * HD;
  for (unsigned i = idx; i < NV; i += stride)
    WvB[i] = f2bf(i < NVr ? Wv[i] : 0.f);
}

// ------- lstm: persistent, 192 blocks, fence-free sc1 point-to-point ------
__global__ __launch_bounds__(256) void lstm_kernel(
    const float* __restrict__ cls, const float* __restrict__ Wih,
    const float* __restrict__ Whh, const float* __restrict__ bih,
    const float* __restrict__ bhh, float* __restrict__ hbuf,
    float* __restrict__ Hall, int* __restrict__ flags) {
  __shared__ float h_lds[8 * PADH];    // current h (or cls), [b][k] padded
  __shared__ float red[4][16][8];      // per-wave partial sums
  __shared__ float gval[16][8];        // final gate values
  const int t = threadIdx.x;
  const int blk = blockIdx.x;
  const int p_ = t & 7;                // row-pair 0..7 (16 rows/block)
  const int s_ = t >> 3;               // k-slice 0..31 (24 k each)
  const int ks = s_ * 24;
  const int r0 = 2 * p_, r1 = r0 + 1;  // local rows; gate=r>>2, unit=r&3
  const int grow0 = (r0 >> 2) * HD + blk * 4 + (r0 & 3);
  const int grow1 = (r1 >> 2) * HD + blk * 4 + (r1 & 3);
  float w0[24], w1[24];
#pragma unroll
  for (int j = 0; j < 24; ++j) {
    w0[j] = Wih[(size_t)grow0 * HD + ks + j];
    w1[j] = Wih[(size_t)grow1 * HD + ks + j];
  }
  float bias = 0.f;
  if (t < 128) {
    int r = t >> 3;
    int gr = (r >> 2) * HD + blk * 4 + (r & 3);
    bias = bih[gr] + bhh[gr];
  }
  float cstate = 0.f;

  // hout_slice: this block's 32-float slice (layout [b*4+ul]); hall_row: [b][768]
  auto do_step = [&](float* __restrict__ hout_slice, float* __restrict__ hall_row) {
    float acc0[8], acc1[8];
#pragma unroll
    for (int b = 0; b < 8; ++b) { acc0[b] = 0.f; acc1[b] = 0.f; }
#pragma unroll
    for (int b = 0; b < 8; ++b) {
      const float* hb = &h_lds[b * PADH + ks];
#pragma unroll
      for (int j4 = 0; j4 < 6; ++j4) {
        f32x4 hv = *reinterpret_cast<const f32x4*>(hb + j4 * 4);
#pragma unroll
        for (int e = 0; e < 4; ++e) {
          acc0[b] = fmaf(w0[j4 * 4 + e], hv[e], acc0[b]);
          acc1[b] = fmaf(w1[j4 * 4 + e], hv[e], acc1[b]);
        }
      }
    }
#pragma unroll
    for (int b = 0; b < 8; ++b) {   // reduce over the wave's 8 k-slices
      acc0[b] += __shfl_xor(acc0[b], 8);
      acc0[b] += __shfl_xor(acc0[b], 16);
      acc0[b] += __shfl_xor(acc0[b], 32);
      acc1[b] += __shfl_xor(acc1[b], 8);
      acc1[b] += __shfl_xor(acc1[b], 16);
      acc1[b] += __shfl_xor(acc1[b], 32);
    }
    const int lane = t & 63, wv = t >> 6;
    if (lane < 8) {
#pragma unroll
      for (int b = 0; b < 8; ++b) {
        red[wv][2 * lane][b] = acc0[b];
        red[wv][2 * lane + 1][b] = acc1[b];
      }
    }
    __syncthreads();
    if (t < 128) {
      int r = t >> 3, b = t & 7;
      gval[r][b] = red[0][r][b] + red[1][r][b] + red[2][r][b] + red[3][r][b] + bias;
    }
    __syncthreads();
    if (t < 32) {
      int ul = t >> 3, b = t & 7;
      float gi = gval[ul][b], gf = gval[4 + ul][b];
      float gg = gval[8 + ul][b], go = gval[12 + ul][b];
      float iv = 1.f / (1.f + expf(-gi));
      float fv = 1.f / (1.f + expf(-gf));
      float gv = tanhf(gg);
      float ov = 1.f / (1.f + expf(-go));
      cstate = fv * cstate + iv * gv;
      float hn = ov * tanhf(cstate);
      st_wt(&hout_slice[b * 4 + ul], hn);        // sc1 write-through to MALL
      if (hall_row) hall_row[(size_t)b * HD + blk * 4 + ul] = hn;  // plain
    }
  };

  // fence-free publish: data stores are sc1 (already headed to the MALL);
  // lane 0 is in the same wave as all 32 storing lanes, so vmcnt(0) waits
  // for their coherence-point acks; then the sc1 flag store cannot pass them.
  auto publish = [&](int gen) {
    if (t == 0) {
      asm volatile("s_waitcnt vmcnt(0)" ::: "memory");
      __hip_atomic_store(&flags[blk], gen, __ATOMIC_RELAXED, __HIP_MEMORY_SCOPE_AGENT);
    }
  };

  // pre-step: h1 = cell(cls, 0, 0) -> gates = cls@Wih^T + (bih+bhh)
  for (int i = t; i < 1536; i += 256) {
    int b = i / 192, c4 = i - b * 192;
    *reinterpret_cast<f32x4*>(&h_lds[b * PADH + c4 * 4]) =
        reinterpret_cast<const f32x4*>(cls)[i];
  }
  __syncthreads();
  do_step(hbuf + 6144 + blk * 32, nullptr);    // h_1 -> parity 1
  publish(1);
  // switch to combined weights W_ih + W_hh (inside the scan, x == h)
#pragma unroll
  for (int j = 0; j < 24; ++j) {
    w0[j] += Whh[(size_t)grow0 * HD + ks + j];
    w1[j] += Whh[(size_t)grow1 * HD + ks + j];
  }
  for (int s = 1; s <= NSTEPS; ++s) {
    if (t < NBL) {
      // wait until block t has published h_s (relaxed sc1 load, no cache ops)
      while (__hip_atomic_load(&flags[t], __ATOMIC_RELAXED, __HIP_MEMORY_SCOPE_AGENT) < s)
        __builtin_amdgcn_s_sleep(1);
    }
    __syncthreads();   // all 192 flags confirmed by someone in this block
    {
      // gather h_s straight from the coherence point: 24 sc1 scalar loads
      // per thread (6144 floats total). float f: src block=f>>5, j=f&31,
      // b=(f>>2)&7, col=(f>>5)*4+(f&3).
      const float* src = hbuf + (s & 1) * 6144;
      float tmp[24];
#pragma unroll
      for (int k = 0; k < 24; ++k) tmp[k] = ld_wt(&src[t + k * 256]);
#pragma unroll
      for (int k = 0; k < 24; ++k) {
        int f = t + k * 256;
        h_lds[((f >> 2) & 7) * PADH + (f >> 5) * 4 + (f & 3)] = tmp[k];
      }
    }
    __syncthreads();
    do_step(hbuf + ((s + 1) & 1) * 6144 + blk * 32,
            Hall + (size_t)(s - 1) * (8 * HD));
    publish(s + 1);
  }
}

// ---------------- head: dense + gelu(erf) + LayerNorm -> T (bf16) ----------
__global__ __launch_bounds__(256) void head_kernel(
    const float* __restrict__ Hall, const float* __restrict__ WdT,
    const float* __restrict__ bd, const float* __restrict__ gamma,
    const float* __restrict__ beta, unsigned short* __restrict__ Tm) {
  __shared__ float hT[HD][16];
  __shared__ float rbuf[4][16];
  __shared__ float mu_s[16], rs_s[16];
  const int t = threadIdx.x;
  const int r0 = blockIdx.x * 16;
  {
    const int row = t & 15, ksl = t >> 4;
    const float* src = Hall + (size_t)(r0 + row) * HD + ksl * 48;
#pragma unroll
    for (int i = 0; i < 12; ++i) {
      f32x4 v = *reinterpret_cast<const f32x4*>(src + i * 4);
      int k = ksl * 48 + i * 4;
      hT[k][row] = v[0]; hT[k + 1][row] = v[1];
      hT[k + 2][row] = v[2]; hT[k + 3][row] = v[3];
    }
  }
  __syncthreads();
  float a0[16], a1[16], a2[16];
#pragma unroll
  for (int r = 0; r < 16; ++r) { a0[r] = 0.f; a1[r] = 0.f; a2[r] = 0.f; }
  for (int k = 0; k < HD; ++k) {
    float wa = WdT[(size_t)k * HD + t];
    float wb = WdT[(size_t)k * HD + t + 256];
    float wc = WdT[(size_t)k * HD + t + 512];
    f32x4 hv4[4];
#pragma unroll
    for (int q = 0; q < 4; ++q)
      hv4[q] = *reinterpret_cast<const f32x4*>(&hT[k][q * 4]);
#pragma unroll
    for (int r = 0; r < 16; ++r) {
      float hv = hv4[r >> 2][r & 3];
      a0[r] = fmaf(wa, hv, a0[r]);
      a1[r] = fmaf(wb, hv, a1[r]);
      a2[r] = fmaf(wc, hv, a2[r]);
    }
  }
  float g0 = gamma[t], g1 = gamma[t + 256], g2 = gamma[t + 512];
  float be0 = beta[t], be1 = beta[t + 256], be2 = beta[t + 512];
  float bd0 = bd[t], bd1 = bd[t + 256], bd2 = bd[t + 512];
#pragma unroll
  for (int r = 0; r < 16; ++r) {
    float x;
    x = a0[r] + bd0; a0[r] = 0.5f * x * (1.f + erff(x * 0.7071067811865476f));
    x = a1[r] + bd1; a1[r] = 0.5f * x * (1.f + erff(x * 0.7071067811865476f));
    x = a2[r] + bd2; a2[r] = 0.5f * x * (1.f + erff(x * 0.7071067811865476f));
  }
  float ps[16];
  const int lane = t & 63, wv = t >> 6;
#pragma unroll
  for (int r = 0; r < 16; ++r) ps[r] = a0[r] + a1[r] + a2[r];
#pragma unroll
  for (int r = 0; r < 16; ++r)
#pragma unroll
    for (int m = 1; m < 64; m <<= 1) ps[r] += __shfl_xor(ps[r], m);
  if (lane == 0) {
#pragma unroll
    for (int r = 0; r < 16; ++r) rbuf[wv][r] = ps[r];
  }
  __syncthreads();
  if (t < 16) mu_s[t] = (rbuf[0][t] + rbuf[1][t] + rbuf[2][t] + rbuf[3][t]) * (1.f / HD);
  __syncthreads();
#pragma unroll
  for (int r = 0; r < 16; ++r) {
    float mu = mu_s[r];
    float d0 = a0[r] - mu, d1 = a1[r] - mu, d2 = a2[r] - mu;
    ps[r] = d0 * d0 + d1 * d1 + d2 * d2;
  }
#pragma unroll
  for (int r = 0; r < 16; ++r)
#pragma unroll
    for (int m = 1; m < 64; m <<= 1) ps[r] += __shfl_xor(ps[r], m);
  if (lane == 0) {
#pragma unroll
    for (int r = 0; r < 16; ++r) rbuf[wv][r] = ps[r];
  }
  __syncthreads();
  if (t < 16)
    rs_s[t] = 1.f / sqrtf((rbuf[0][t] + rbuf[1][t] + rbuf[2][t] + rbuf[3][t]) * (1.f / HD) + 1e-12f);
  __syncthreads();
#pragma unroll
  for (int r = 0; r < 16; ++r) {
    float mu = mu_s[r], rs = rs_s[r];
    size_t ro = (size_t)(r0 + r) * HD;
    Tm[ro + t]       = f2bf((a0[r] - mu) * rs * g0 + be0);
    Tm[ro + t + 256] = f2bf((a1[r] - mu) * rs * g1 + be1);
    Tm[ro + t + 512] = f2bf((a2[r] - mu) * rs * g2 + be2);
  }
}

// ---------------- decoder GEMM: out = T @ WvB^T + bvoc  (bf16 MFMA) -------
__global__ __launch_bounds__(256) void gemm_kernel(
    const unsigned short* __restrict__ Tm, const unsigned short* __restrict__ Wv,
    const float* __restrict__ bvoc, float* __restrict__ out) {
  __shared__ unsigned short As[128 * 64];
  __shared__ unsigned short Bs[128 * 64];
  const int t = threadIdx.x;
  const int lane = t & 63, wid = t >> 6;
  const int wm = wid >> 1, wn = wid & 1;
  const int m0 = blockIdx.y * 128, n0 = blockIdx.x * 128;
  const int lrow = lane & 15, lgrp = lane >> 4;
  f32x4 acc[4][4] = {};
  for (int kt = 0; kt < HD; kt += 64) {
#pragma unroll
    for (int it = 0; it < 4; ++it) {
      int slot = it * 256 + t;
      int row = slot >> 3, g = slot & 7;
      int sg = g ^ (row & 7);                       // pre-swizzled source
      const unsigned short* sa = Tm + (size_t)(m0 + row) * HD + kt + sg * 8;
      const unsigned short* sb = Wv + (size_t)(n0 + row) * HD + kt + sg * 8;
      unsigned short* da = &As[(it * 256 + wid * 64) * 8];  // wave-uniform base
      unsigned short* db = &Bs[(it * 256 + wid * 64) * 8];
      gl_lds16(sa, da);
      gl_lds16(sb, db);
    }
    __syncthreads();
#pragma unroll
    for (int kk = 0; kk < 2; ++kk) {
      short8 af[4], bfr[4];
#pragma unroll
      for (int i = 0; i < 4; ++i) {
        int row = wm * 64 + i * 16 + lrow;
        int gg = (kk * 4 + lgrp) ^ (row & 7);       // swizzled read
        af[i] = *reinterpret_cast<const short8*>(&As[row * 64 + gg * 8]);
      }
#pragma unroll
      for (int j = 0; j < 4; ++j) {
        int row = wn * 64 + j * 16 + lrow;
        int gg = (kk * 4 + lgrp) ^ (row & 7);
        bfr[j] = *reinterpret_cast<const short8*>(&Bs[row * 64 + gg * 8]);
      }
#pragma unroll
      for (int i = 0; i < 4; ++i)
#pragma unroll
        for (int j = 0; j < 4; ++j)
          acc[i][j] = __builtin_amdgcn_mfma_f32_16x16x32_bf16(af[i], bfr[j], acc[i][j], 0, 0, 0);
    }
    __syncthreads();
  }
#pragma unroll
  for (int j = 0; j < 4; ++j) {
    int col = n0 + wn * 64 + j * 16 + lrow;
    bool cok = col < VOC;
    float bv = cok ? bvoc[col] : 0.f;
#pragma unroll
    for (int i = 0; i < 4; ++i) {
      int rbase = m0 + wm * 64 + i * 16 + lgrp * 4;
#pragma unroll
      for (int e = 0; e < 4; ++e) {
        int row = rbase + e;
        if (cok && row < MROWS) out[(size_t)row * VOC + col] = acc[i][j][e] + bv;
      }
    }
  }
}

extern "C" void kernel_launch(void* const* d_in, const int* in_sizes, int n_in,
                              void* d_out, int out_size, void* d_ws, size_t ws_size,
                              hipStream_t stream) {
  (void)in_sizes; (void)n_in; (void)out_size; (void)ws_size;
  const float* cls  = (const float*)d_in[0];
  const float* Wih  = (const float*)d_in[1];
  const float* Whh  = (const float*)d_in[2];
  const float* bih  = (const float*)d_in[3];
  const float* bhh  = (const float*)d_in[4];
  const float* Wd   = (const float*)d_in[5];
  const float* bd   = (const float*)d_in[6];
  const float* gmm  = (const float*)d_in[7];
  const float* bet  = (const float*)d_in[8];
  const float* Wv   = (const float*)d_in[9];
  const float* bvoc = (const float*)d_in[10];
  char* ws = (char*)d_ws;
  int*   flags = (int*)(ws);
  float* hbuf  = (float*)(ws + OFF_HBUF);
  float* Hall  = (float*)(ws + OFF_HALL);
  float* WdT   = (float*)(ws + OFF_WDT);
  unsigned short* Tm  = (unsigned short*)(ws + OFF_T);
  unsigned short* WvB = (unsigned short*)(ws + OFF_WV);
  float* out = (float*)d_out;

  hipLaunchKernelGGL(prep_kernel, dim3(4096), dim3(256), 0, stream, Wd, WdT, Wv, WvB, flags);
  hipLaunchKernelGGL(lstm_kernel, dim3(NBL), dim3(256), 0, stream,
                     cls, Wih, Whh, bih, bhh, hbuf, Hall, flags);
  hipLaunchKernelGGL(head_kernel, dim3(MPAD / 16), dim3(256), 0, stream,
                     Hall, WdT, bd, gmm, bet, Tm);
  hipLaunchKernelGGL(gemm_kernel, dim3(VOCP / 128, MPAD / 128), dim3(256), 0, stream,
                     Tm, WvB, bvoc, out);
}

// Round 7
// 2171.679 us; speedup vs baseline: 9.0297x; 1.6900x over previous
//
#include <hip/hip_runtime.h>
#include <hip/hip_bf16.h>
#include <cstdint>

#define HD 768
#define VOC 21128
#define VOCP 21248
#define NSTEPS 511
#define MROWS 4088      // 511*8
#define MPAD 4096
#define NBL 192         // lstm blocks (co-resident, 192 < 256 CUs)

typedef float f32x4 __attribute__((ext_vector_type(4)));
typedef short short8 __attribute__((ext_vector_type(8)));

// ---- workspace layout (bytes) ----
// 0        : (unused)                                                (768)
// 768      : hw[2][6144] u32  packed h words [tag16|fp16], [u][b]    (49152)
// 49920    : Hall[4088][768] f32                                     (12558336)
// 12632576 : WdT[768][768] f32                                       (2359296)
// 14991872 : T[4096][768] bf16                                       (6291456)
// 21283328 : WvB[21248][768] bf16                                    (32636928) -> end 53920256
#define OFF_HW   768
#define OFF_HALL 49920
#define OFF_WDT  12632576ULL
#define OFF_T    14991872ULL
#define OFF_WV   21283328ULL
#define PADH 772        // h_lds row stride (bank-conflict pad)

__device__ __forceinline__ unsigned short f2bf(float x) {
  unsigned u = __float_as_uint(x);
  u += 0x7FFFu + ((u >> 16) & 1u);   // RNE
  return (unsigned short)(u >> 16);
}

__device__ __forceinline__ void gl_lds16(const void* g, void* l) {
  __builtin_amdgcn_global_load_lds(
      (const __attribute__((address_space(1))) void*)g,
      (__attribute__((address_space(3))) void*)l, 16, 0, 0);
}

// relaxed agent-scope (sc1): coherent-point traffic, no cache-wide ops
__device__ __forceinline__ void st_u32(uint32_t* p, uint32_t v) {
  __hip_atomic_store(p, v, __ATOMIC_RELAXED, __HIP_MEMORY_SCOPE_AGENT);
}
__device__ __forceinline__ uint32_t ld_u32(const uint32_t* p) {
  return __hip_atomic_load(p, __ATOMIC_RELAXED, __HIP_MEMORY_SCOPE_AGENT);
}

// wave-local xor-swizzles (within 32-lane halves; BitMode patterns)
__device__ __forceinline__ float swz8(float x) {
  return __int_as_float(__builtin_amdgcn_ds_swizzle(__float_as_int(x), 0x201F));
}
__device__ __forceinline__ float swz16(float x) {
  return __int_as_float(__builtin_amdgcn_ds_swizzle(__float_as_int(x), 0x401F));
}

// overflow-safe fast activations (rcp(inf)=0 gives exact saturation)
__device__ __forceinline__ float sigf(float x) {
  return __builtin_amdgcn_rcpf(1.f + __expf(-x));
}
__device__ __forceinline__ float tanhf_fast(float x) {
  float ax = fabsf(x);
  float e = __expf(-2.f * ax);                       // in (0,1], no overflow
  float t = (1.f - e) * __builtin_amdgcn_rcpf(1.f + e);
  return copysignf(t, x);
}

// ---------------- prep: WdT transpose, Wv->bf16 (padded), hw zero ---------
__global__ __launch_bounds__(256) void prep_kernel(
    const float* __restrict__ Wd, float* __restrict__ WdT,
    const float* __restrict__ Wv, unsigned short* __restrict__ WvB,
    uint32_t* __restrict__ hw) {
  unsigned idx = blockIdx.x * 256 + threadIdx.x;
  unsigned stride = gridDim.x * 256;
  for (unsigned i = idx; i < 12288; i += stride) hw[i] = 0;   // stale-tag kill
  for (unsigned i = idx; i < HD * HD; i += stride) {
    unsigned k = i / HD, j = i - k * HD;
    WdT[i] = Wd[j * HD + k];           // WdT[k][j] = Wd[j][k]
  }
  const unsigned NV = (unsigned)VOCP * HD, NVr = (unsigned)VOC * HD;
  for (unsigned i = idx; i < NV; i += stride)
    WvB[i] = f2bf(i < NVr ? Wv[i] : 0.f);
}

// ------ lstm: persistent, 192 blocks, self-validating word protocol -------
__global__ __launch_bounds__(256) void lstm_kernel(
    const float* __restrict__ cls, const float* __restrict__ Wih,
    const float* __restrict__ Whh, const float* __restrict__ bih,
    const float* __restrict__ bhh, uint32_t* __restrict__ hw,
    float* __restrict__ Hall) {
  __shared__ float h_lds[8 * PADH];       // current h (or cls), [b][u] padded
  __shared__ float red[4][2][16][8];      // [wave][half][row][b] partials
  __shared__ float sbias[16];             // combined gate biases, local rows
  const int t = threadIdx.x;
  const int blk = blockIdx.x;
  const int p_ = t & 7;                // row-pair 0..7 (16 rows/block)
  const int s_ = t >> 3;               // k-slice 0..31 (24 k each)
  const int ks = s_ * 24;
  const int r0 = 2 * p_, r1 = r0 + 1;  // local rows; gate=r>>2, unit=r&3
  const int grow0 = (r0 >> 2) * HD + blk * 4 + (r0 & 3);
  const int grow1 = (r1 >> 2) * HD + blk * 4 + (r1 & 3);
  float w0[24], w1[24];
#pragma unroll
  for (int j = 0; j < 24; ++j) {
    w0[j] = Wih[(size_t)grow0 * HD + ks + j];
    w1[j] = Wih[(size_t)grow1 * HD + ks + j];
  }
  if (t < 16) {
    int gr = (t >> 2) * HD + blk * 4 + (t & 3);
    sbias[t] = bih[gr] + bhh[gr];
  }
  float cstate = 0.f;
  const int lane = t & 63, wv = t >> 6, hf = (lane >> 5);

  // one LSTM cell step; publishes packed [tag|fp16(h)] words
  auto do_step = [&](uint32_t* __restrict__ hw_out, int tag,
                     float* __restrict__ hall_row) {
    float acc0[8], acc1[8];
#pragma unroll
    for (int b = 0; b < 8; ++b) { acc0[b] = 0.f; acc1[b] = 0.f; }
#pragma unroll
    for (int b = 0; b < 8; ++b) {
      const float* hb = &h_lds[b * PADH + ks];
#pragma unroll
      for (int j4 = 0; j4 < 6; ++j4) {
        f32x4 hv = *reinterpret_cast<const f32x4*>(hb + j4 * 4);
#pragma unroll
        for (int e = 0; e < 4; ++e) {
          acc0[b] = fmaf(w0[j4 * 4 + e], hv[e], acc0[b]);
          acc1[b] = fmaf(w1[j4 * 4 + e], hv[e], acc1[b]);
        }
      }
    }
    // reduce over the wave's 8 k-slices: 2 swizzle rounds -> per-half sums
#pragma unroll
    for (int b = 0; b < 8; ++b) {
      acc0[b] += swz8(acc0[b]);  acc0[b] += swz16(acc0[b]);
      acc1[b] += swz8(acc1[b]);  acc1[b] += swz16(acc1[b]);
    }
    if ((lane & 31) < 8) {
#pragma unroll
      for (int b = 0; b < 8; ++b) {
        red[wv][hf][r0][b] = acc0[b];
        red[wv][hf][r1][b] = acc1[b];
      }
    }
    __syncthreads();                      // red complete
    if (t < 32) {
      int ul = t >> 3, b = t & 7;
      float gs[4];
#pragma unroll
      for (int g = 0; g < 4; ++g) {
        int r = g * 4 + ul;
        float s = sbias[r];
#pragma unroll
        for (int w2 = 0; w2 < 4; ++w2) s += red[w2][0][r][b] + red[w2][1][r][b];
        gs[g] = s;
      }
      float iv = sigf(gs[0]);
      float fv = sigf(gs[1]);
      float gv = tanhf_fast(gs[2]);
      float ov = sigf(gs[3]);
      cstate = fv * cstate + iv * gv;
      float hn = ov * tanhf_fast(cstate);
      // pack [tag | fp16(hn)] -- single atomic word, publish immediately
      union { _Float16 f; unsigned short u; } cv;
      cv.f = (_Float16)hn;
      st_u32(&hw_out[(blk * 4 + ul) * 8 + b],
             ((uint32_t)tag << 16) | (uint32_t)cv.u);
      if (hall_row) hall_row[(size_t)b * HD + blk * 4 + ul] = hn;  // plain f32
    }
  };

  // pre-step: h1 = cell(cls, 0, 0) -> gates = cls@Wih^T + (bih+bhh)
  for (int i = t; i < 1536; i += 256) {
    int b = i / 192, c4 = i - b * 192;
    *reinterpret_cast<f32x4*>(&h_lds[b * PADH + c4 * 4]) =
        reinterpret_cast<const f32x4*>(cls)[i];
  }
  __syncthreads();
  do_step(hw + 6144, 1, nullptr);        // h_1 -> parity 1, tag 1
  // switch to combined weights W_ih + W_hh (inside the scan, x == h)
#pragma unroll
  for (int j = 0; j < 24; ++j) {
    w0[j] += Whh[(size_t)grow0 * HD + ks + j];
    w1[j] += Whh[(size_t)grow1 * HD + ks + j];
  }
  for (int s = 1; s <= NSTEPS; ++s) {
    // poll own 24 words of h_s (word f: unit=f>>3, batch=f&7); data IS flag
    const uint32_t* src = hw + (s & 1) * 6144;
    uint32_t w[24];
    bool ok;
    do {
      ok = true;
#pragma unroll
      for (int k = 0; k < 24; ++k) {
        w[k] = ld_u32(&src[t + k * 256]);
        if ((w[k] >> 16) != (uint32_t)s) ok = false;
      }
    } while (!ok);
#pragma unroll
    for (int k = 0; k < 24; ++k) {
      int f = t + k * 256;
      union { unsigned short u; _Float16 f16; } cv;
      cv.u = (unsigned short)(w[k] & 0xFFFFu);
      h_lds[(f & 7) * PADH + (f >> 3)] = (float)cv.f16;
    }
    __syncthreads();                     // h_s staged in LDS
    do_step(hw + ((s + 1) & 1) * 6144, s + 1,
            Hall + (size_t)(s - 1) * (8 * HD));
  }
}

// ---------------- head: dense + gelu(erf) + LayerNorm -> T (bf16) ----------
__global__ __launch_bounds__(256) void head_kernel(
    const float* __restrict__ Hall, const float* __restrict__ WdT,
    const float* __restrict__ bd, const float* __restrict__ gamma,
    const float* __restrict__ beta, unsigned short* __restrict__ Tm) {
  __shared__ float hT[HD][16];
  __shared__ float rbuf[4][16];
  __shared__ float mu_s[16], rs_s[16];
  const int t = threadIdx.x;
  const int r0 = blockIdx.x * 16;
  {
    const int row = t & 15, ksl = t >> 4;
    const float* src = Hall + (size_t)(r0 + row) * HD + ksl * 48;
#pragma unroll
    for (int i = 0; i < 12; ++i) {
      f32x4 v = *reinterpret_cast<const f32x4*>(src + i * 4);
      int k = ksl * 48 + i * 4;
      hT[k][row] = v[0]; hT[k + 1][row] = v[1];
      hT[k + 2][row] = v[2]; hT[k + 3][row] = v[3];
    }
  }
  __syncthreads();
  float a0[16], a1[16], a2[16];
#pragma unroll
  for (int r = 0; r < 16; ++r) { a0[r] = 0.f; a1[r] = 0.f; a2[r] = 0.f; }
  for (int k = 0; k < HD; ++k) {
    float wa = WdT[(size_t)k * HD + t];
    float wb = WdT[(size_t)k * HD + t + 256];
    float wc = WdT[(size_t)k * HD + t + 512];
    f32x4 hv4[4];
#pragma unroll
    for (int q = 0; q < 4; ++q)
      hv4[q] = *reinterpret_cast<const f32x4*>(&hT[k][q * 4]);
#pragma unroll
    for (int r = 0; r < 16; ++r) {
      float hv = hv4[r >> 2][r & 3];
      a0[r] = fmaf(wa, hv, a0[r]);
      a1[r] = fmaf(wb, hv, a1[r]);
      a2[r] = fmaf(wc, hv, a2[r]);
    }
  }
  float g0 = gamma[t], g1 = gamma[t + 256], g2 = gamma[t + 512];
  float be0 = beta[t], be1 = beta[t + 256], be2 = beta[t + 512];
  float bd0 = bd[t], bd1 = bd[t + 256], bd2 = bd[t + 512];
#pragma unroll
  for (int r = 0; r < 16; ++r) {
    float x;
    x = a0[r] + bd0; a0[r] = 0.5f * x * (1.f + erff(x * 0.7071067811865476f));
    x = a1[r] + bd1; a1[r] = 0.5f * x * (1.f + erff(x * 0.7071067811865476f));
    x = a2[r] + bd2; a2[r] = 0.5f * x * (1.f + erff(x * 0.7071067811865476f));
  }
  float ps[16];
  const int lane = t & 63, wv = t >> 6;
#pragma unroll
  for (int r = 0; r < 16; ++r) ps[r] = a0[r] + a1[r] + a2[r];
#pragma unroll
  for (int r = 0; r < 16; ++r)
#pragma unroll
    for (int m = 1; m < 64; m <<= 1) ps[r] += __shfl_xor(ps[r], m);
  if (lane == 0) {
#pragma unroll
    for (int r = 0; r < 16; ++r) rbuf[wv][r] = ps[r];
  }
  __syncthreads();
  if (t < 16) mu_s[t] = (rbuf[0][t] + rbuf[1][t] + rbuf[2][t] + rbuf[3][t]) * (1.f / HD);
  __syncthreads();
#pragma unroll
  for (int r = 0; r < 16; ++r) {
    float mu = mu_s[r];
    float d0 = a0[r] - mu, d1 = a1[r] - mu, d2 = a2[r] - mu;
    ps[r] = d0 * d0 + d1 * d1 + d2 * d2;
  }
#pragma unroll
  for (int r = 0; r < 16; ++r)
#pragma unroll
    for (int m = 1; m < 64; m <<= 1) ps[r] += __shfl_xor(ps[r], m);
  if (lane == 0) {
#pragma unroll
    for (int r = 0; r < 16; ++r) rbuf[wv][r] = ps[r];
  }
  __syncthreads();
  if (t < 16)
    rs_s[t] = 1.f / sqrtf((rbuf[0][t] + rbuf[1][t] + rbuf[2][t] + rbuf[3][t]) * (1.f / HD) + 1e-12f);
  __syncthreads();
#pragma unroll
  for (int r = 0; r < 16; ++r) {
    float mu = mu_s[r], rs = rs_s[r];
    size_t ro = (size_t)(r0 + r) * HD;
    Tm[ro + t]       = f2bf((a0[r] - mu) * rs * g0 + be0);
    Tm[ro + t + 256] = f2bf((a1[r] - mu) * rs * g1 + be1);
    Tm[ro + t + 512] = f2bf((a2[r] - mu) * rs * g2 + be2);
  }
}

// ---------------- decoder GEMM: out = T @ WvB^T + bvoc  (bf16 MFMA) -------
__global__ __launch_bounds__(256) void gemm_kernel(
    const unsigned short* __restrict__ Tm, const unsigned short* __restrict__ Wv,
    const float* __restrict__ bvoc, float* __restrict__ out) {
  __shared__ unsigned short As[128 * 64];
  __shared__ unsigned short Bs[128 * 64];
  const int t = threadIdx.x;
  const int lane = t & 63, wid = t >> 6;
  const int wm = wid >> 1, wn = wid & 1;
  const int m0 = blockIdx.y * 128, n0 = blockIdx.x * 128;
  const int lrow = lane & 15, lgrp = lane >> 4;
  f32x4 acc[4][4] = {};
  for (int kt = 0; kt < HD; kt += 64) {
#pragma unroll
    for (int it = 0; it < 4; ++it) {
      int slot = it * 256 + t;
      int row = slot >> 3, g = slot & 7;
      int sg = g ^ (row & 7);                       // pre-swizzled source
      const unsigned short* sa = Tm + (size_t)(m0 + row) * HD + kt + sg * 8;
      const unsigned short* sb = Wv + (size_t)(n0 + row) * HD + kt + sg * 8;
      unsigned short* da = &As[(it * 256 + wid * 64) * 8];  // wave-uniform base
      unsigned short* db = &Bs[(it * 256 + wid * 64) * 8];
      gl_lds16(sa, da);
      gl_lds16(sb, db);
    }
    __syncthreads();
#pragma unroll
    for (int kk = 0; kk < 2; ++kk) {
      short8 af[4], bfr[4];
#pragma unroll
      for (int i = 0; i < 4; ++i) {
        int row = wm * 64 + i * 16 + lrow;
        int gg = (kk * 4 + lgrp) ^ (row & 7);       // swizzled read
        af[i] = *reinterpret_cast<const short8*>(&As[row * 64 + gg * 8]);
      }
#pragma unroll
      for (int j = 0; j < 4; ++j) {
        int row = wn * 64 + j * 16 + lrow;
        int gg = (kk * 4 + lgrp) ^ (row & 7);
        bfr[j] = *reinterpret_cast<const short8*>(&Bs[row * 64 + gg * 8]);
      }
#pragma unroll
      for (int i = 0; i < 4; ++i)
#pragma unroll
        for (int j = 0; j < 4; ++j)
          acc[i][j] = __builtin_amdgcn_mfma_f32_16x16x32_bf16(af[i], bfr[j], acc[i][j], 0, 0, 0);
    }
    __syncthreads();
  }
#pragma unroll
  for (int j = 0; j < 4; ++j) {
    int col = n0 + wn * 64 + j * 16 + lrow;
    bool cok = col < VOC;
    float bv = cok ? bvoc[col] : 0.f;
#pragma unroll
    for (int i = 0; i < 4; ++i) {
      int rbase = m0 + wm * 64 + i * 16 + lgrp * 4;
#pragma unroll
      for (int e = 0; e < 4; ++e) {
        int row = rbase + e;
        if (cok && row < MROWS) out[(size_t)row * VOC + col] = acc[i][j][e] + bv;
      }
    }
  }
}

extern "C" void kernel_launch(void* const* d_in, const int* in_sizes, int n_in,
                              void* d_out, int out_size, void* d_ws, size_t ws_size,
                              hipStream_t stream) {
  (void)in_sizes; (void)n_in; (void)out_size; (void)ws_size;
  const float* cls  = (const float*)d_in[0];
  const float* Wih  = (const float*)d_in[1];
  const float* Whh  = (const float*)d_in[2];
  const float* bih  = (const float*)d_in[3];
  const float* bhh  = (const float*)d_in[4];
  const float* Wd   = (const float*)d_in[5];
  const float* bd   = (const float*)d_in[6];
  const float* gmm  = (const float*)d_in[7];
  const float* bet  = (const float*)d_in[8];
  const float* Wv   = (const float*)d_in[9];
  const float* bvoc = (const float*)d_in[10];
  char* ws = (char*)d_ws;
  uint32_t* hw   = (uint32_t*)(ws + OFF_HW);
  float* Hall  = (float*)(ws + OFF_HALL);
  float* WdT   = (float*)(ws + OFF_WDT);
  unsigned short* Tm  = (unsigned short*)(ws + OFF_T);
  unsigned short* WvB = (unsigned short*)(ws + OFF_WV);
  float* out = (float*)d_out;

  hipLaunchKernelGGL(prep_kernel, dim3(4096), dim3(256), 0, stream, Wd, WdT, Wv, WvB, hw);
  hipLaunchKernelGGL(lstm_kernel, dim3(NBL), dim3(256), 0, stream,
                     cls, Wih, Whh, bih, bhh, hw, Hall);
  hipLaunchKernelGGL(head_kernel, dim3(MPAD / 16), dim3(256), 0, stream,
                     Hall, WdT, bd, gmm, bet, Tm);
  hipLaunchKernelGGL(gemm_kernel, dim3(VOCP / 128, MPAD / 128), dim3(256), 0, stream,
                     Tm, WvB, bvoc, out);
}